// Round 6
// baseline (257.235 us; speedup 1.0000x reference)
//
#include <hip/hip_runtime.h>
#include <math.h>

#define NPTS 16384
#define NSMP 8192          // 8 * 1024
#define KNN 10
#define QPB 8              // queries per block (shared by all waves)
#define WAVES 8            // waves per block = point-range splits
#define SLICE (NPTS / WAVES)   // 2048 points per wave
#define ITER2 (SLICE / 128)    // 16 iterations of 128 points (2 per lane)
#define CAP 256            // candidate buffer capacity per query

// order-preserving float -> uint bijection
__device__ __forceinline__ unsigned mapf(float f) {
    unsigned u = __float_as_uint(f);
    return (u & 0x80000000u) ? ~u : (u | 0x80000000u);
}
__device__ __forceinline__ float unmapf(unsigned k) {
    unsigned u = (k & 0x80000000u) ? (k ^ 0x80000000u) : ~k;
    return __uint_as_float(u);
}

// pack xyz -> (x, y, z, |p|^2) float4, one thread per 4 points
__global__ __launch_bounds__(256) void pack_kernel(const float* __restrict__ xyz,
                                                   float4* __restrict__ pk) {
    const int t = blockIdx.x * 256 + threadIdx.x;        // 32768 threads
    const float4* src = (const float4*)xyz;
    const float4 a = src[t * 3 + 0];
    const float4 b = src[t * 3 + 1];
    const float4 c = src[t * 3 + 2];
    pk[t * 4 + 0] = make_float4(a.x, a.y, a.z, fmaf(a.x, a.x, fmaf(a.y, a.y, a.z * a.z)));
    pk[t * 4 + 1] = make_float4(a.w, b.x, b.y, fmaf(a.w, a.w, fmaf(b.x, b.x, b.y * b.y)));
    pk[t * 4 + 2] = make_float4(b.z, b.w, c.x, fmaf(b.z, b.z, fmaf(b.w, b.w, c.x * c.x)));
    pk[t * 4 + 3] = make_float4(c.y, c.z, c.w, fmaf(c.y, c.y, fmaf(c.z, c.z, c.w * c.w)));
}

__global__ __launch_bounds__(512, 8) void knn_kernel(
    const float4* __restrict__ pk,
    const float* __restrict__ xyz,
    const float* __restrict__ sxyz,
    const float* __restrict__ temp,
    float* __restrict__ out)
{
    __shared__ float minBuf[QPB][WAVES * 64];   // 16 KB: per-(wave,lane) substream minima
    __shared__ float tauS[QPB];
    __shared__ int   cnt[QPB];
    __shared__ float candD[QPB][CAP];           // 8 KB
    __shared__ int   candI[QPB][CAP];           // 8 KB

    const int lane  = threadIdx.x & 63;
    const int w     = threadIdx.x >> 6;         // wave id = point split id (0..7)
    const int qbase = blockIdx.x * QPB;
    const int b     = qbase >> 10;              // batch

    if (threadIdx.x < QPB) cnt[threadIdx.x] = 0;

    // queries, premultiplied by -2 for d' = |p|^2 - 2 p.q
    float nqx[QPB], nqy[QPB], nqz[QPB];
    #pragma unroll
    for (int q = 0; q < QPB; ++q) {
        const float* s = sxyz + (size_t)(qbase + q) * 3;
        nqx[q] = -2.f * s[0]; nqy[q] = -2.f * s[1]; nqz[q] = -2.f * s[2];
    }

    const float4* pw = pk + (size_t)b * NPTS + (size_t)w * SLICE + lane;

    // ---------------- pass A: branchless per-lane running min, 2 pts/lane/iter ----------------
    float mnA[QPB], mnB[QPB];
    #pragma unroll
    for (int q = 0; q < QPB; ++q) { mnA[q] = INFINITY; mnB[q] = INFINITY; }

    #pragma unroll 4
    for (int j = 0; j < ITER2; ++j) {
        const float4 p0 = pw[j * 128];          // coalesced dwordx4, L2-resident
        const float4 p1 = pw[j * 128 + 64];
        #pragma unroll
        for (int q = 0; q < QPB; ++q) {
            const float dA = fmaf(p0.x, nqx[q], fmaf(p0.y, nqy[q], fmaf(p0.z, nqz[q], p0.w)));
            const float dB = fmaf(p1.x, nqx[q], fmaf(p1.y, nqy[q], fmaf(p1.z, nqz[q], p1.w)));
            mnA[q] = fminf(mnA[q], dA);
            mnB[q] = fminf(mnB[q], dB);
        }
    }
    #pragma unroll
    for (int q = 0; q < QPB; ++q) minBuf[q][w * 64 + lane] = fminf(mnA[q], mnB[q]);
    __syncthreads();

    // ------- threshold: wave w extracts 10th smallest of 512 minima (query w) -------
    {
        float r[8];
        #pragma unroll
        for (int k = 0; k < 8; ++k) r[k] = minBuf[w][lane + k * 64];
        float g = INFINITY;
        for (int kk = 0; kk < KNN; ++kk) {
            float v = r[0];
            #pragma unroll
            for (int k = 1; k < 8; ++k) v = fminf(v, r[k]);
            g = v;
            #pragma unroll
            for (int off = 32; off >= 1; off >>= 1) g = fminf(g, __shfl_xor(g, off));
            const unsigned long long mm = __ballot(v == g);
            if (lane == (int)__builtin_ctzll(mm)) {   // remove one instance
                if      (r[0] == g) r[0] = INFINITY;
                else if (r[1] == g) r[1] = INFINITY;
                else if (r[2] == g) r[2] = INFINITY;
                else if (r[3] == g) r[3] = INFINITY;
                else if (r[4] == g) r[4] = INFINITY;
                else if (r[5] == g) r[5] = INFINITY;
                else if (r[6] == g) r[6] = INFINITY;
                else                r[7] = INFINITY;
            }
        }
        if (lane == 0) tauS[w] = g;   // 10th smallest substream min >= d10 (provable)
    }
    __syncthreads();

    float tau[QPB];
    #pragma unroll
    for (int q = 0; q < QPB; ++q) tau[q] = tauS[q];

    // ---------------- pass B: filter d <= tau, parallel compaction ----------------
    const int sbase = w * SLICE;
    #pragma unroll 2
    for (int j = 0; j < ITER2; ++j) {
        const float4 p0 = pw[j * 128];
        const float4 p1 = pw[j * 128 + 64];
        float dA[QPB], dB[QPB];
        #pragma unroll
        for (int q = 0; q < QPB; ++q) {
            dA[q] = fmaf(p0.x, nqx[q], fmaf(p0.y, nqy[q], fmaf(p0.z, nqz[q], p0.w)));
            dB[q] = fmaf(p1.x, nqx[q], fmaf(p1.y, nqy[q], fmaf(p1.z, nqz[q], p1.w)));
        }
        float eA = dA[0] - tau[0], eB = dB[0] - tau[0];
        #pragma unroll
        for (int q = 1; q < QPB; ++q) {
            eA = fminf(eA, dA[q] - tau[q]);
            eB = fminf(eB, dB[q] - tau[q]);
        }
        if (__ballot(fminf(eA, eB) <= 0.f)) {
            #pragma unroll
            for (int q = 0; q < QPB; ++q) {
                const unsigned long long mA = __ballot(dA[q] <= tau[q]);
                const unsigned long long mB = __ballot(dB[q] <= tau[q]);
                if (mA | mB) {
                    const int cA  = __popcll(mA);
                    const int tot = cA + __popcll(mB);
                    const int leader = (int)__builtin_ctzll(mA | mB);
                    int base = 0;
                    if (lane == leader) base = atomicAdd(&cnt[q], tot);
                    base = __shfl(base, leader);
                    if (dA[q] <= tau[q]) {
                        const int slot = base + __popcll(mA & ((1ull << lane) - 1ull));
                        if (slot < CAP) { candD[q][slot] = dA[q]; candI[q][slot] = sbase + j * 128 + lane; }
                    }
                    if (dB[q] <= tau[q]) {
                        const int slot = base + cA + __popcll(mB & ((1ull << lane) - 1ull));
                        if (slot < CAP) { candD[q][slot] = dB[q]; candI[q][slot] = sbase + j * 128 + 64 + lane; }
                    }
                }
            }
        }
    }
    __syncthreads();

    // ------- final: wave w selects top-10 of query w's candidates (canonical) -------
    {
        const int q   = w;
        const int gid = qbase + q;
        const int c   = min(cnt[q], CAP);       // c >= 10 guaranteed

        unsigned long long k0 = (lane       < c) ? ((unsigned long long)mapf(candD[q][lane      ]) << 32) | (unsigned)candI[q][lane      ] : ~0ull;
        unsigned long long k1 = (lane +  64 < c) ? ((unsigned long long)mapf(candD[q][lane +  64]) << 32) | (unsigned)candI[q][lane +  64] : ~0ull;
        unsigned long long k2 = (lane + 128 < c) ? ((unsigned long long)mapf(candD[q][lane + 128]) << 32) | (unsigned)candI[q][lane + 128] : ~0ull;
        unsigned long long k3 = (lane + 192 < c) ? ((unsigned long long)mapf(candD[q][lane + 192]) << 32) | (unsigned)candI[q][lane + 192] : ~0ull;

        unsigned long long sel = ~0ull;
        for (int k = 0; k < KNN; ++k) {
            const unsigned long long a01 = (k0 < k1) ? k0 : k1;
            const unsigned long long a23 = (k2 < k3) ? k2 : k3;
            const unsigned long long v   = (a01 < a23) ? a01 : a23;
            unsigned long long g = v;
            #pragma unroll
            for (int off = 32; off >= 1; off >>= 1) {
                const unsigned long long o = __shfl_xor(g, off);
                g = (o < g) ? o : g;
            }
            if (lane == k) sel = g;             // lane k holds k-th smallest (sorted)
            const unsigned long long mm = __ballot(v == g);
            if (lane == (int)__builtin_ctzll(mm)) {
                if      (k0 == g) k0 = ~0ull;
                else if (k1 == g) k1 = ~0ull;
                else if (k2 == g) k2 = ~0ull;
                else              k3 = ~0ull;
            }
        }

        // epilogue: d2 = max(d' + |q|^2, 0), softmax over 10, weighted coord sum
        const float* s = sxyz + (size_t)gid * 3;
        const float q2 = fmaf(s[0], s[0], fmaf(s[1], s[1], s[2] * s[2]));
        const float dp = unmapf((unsigned)(sel >> 32));
        const float d2 = fmaxf(dp + q2, 0.f);
        const float dmin = __shfl(d2, 0);       // lane 0 = smallest (sorted order)
        const float t = temp[0];
        const float invt2 = 1.0f / (t * t);
        float wgt = 0.f, px = 0.f, py = 0.f, pz = 0.f;
        if (lane < KNN) {
            wgt = __expf((dmin - d2) * invt2);
            const int idx = (int)(unsigned)(sel & 0xFFFFFFFFull);
            const float* pp = xyz + ((size_t)b * NPTS + idx) * 3;
            px = pp[0]; py = pp[1]; pz = pp[2];
        }
        float sw = wgt, sx = wgt * px, sy = wgt * py, sz = wgt * pz;
        #pragma unroll
        for (int off = 8; off >= 1; off >>= 1) {
            sw += __shfl_xor(sw, off);
            sx += __shfl_xor(sx, off);
            sy += __shfl_xor(sy, off);
            sz += __shfl_xor(sz, off);
        }
        if (lane == 0) {
            const float inv = 1.0f / sw;
            out[(size_t)gid * 3 + 0] = sx * inv;
            out[(size_t)gid * 3 + 1] = sy * inv;
            out[(size_t)gid * 3 + 2] = sz * inv;
            if (gid == 0) out[NSMP * 3] = t;    // tuple output 2: temp
        }
    }
}

extern "C" void kernel_launch(void* const* d_in, const int* in_sizes, int n_in,
                              void* d_out, int out_size, void* d_ws, size_t ws_size,
                              hipStream_t stream) {
    const float* xyz  = (const float*)d_in[0];   // [8,16384,3]
    const float* sxyz = (const float*)d_in[1];   // [8,1024,3]
    const float* temp = (const float*)d_in[2];   // scalar
    float* out = (float*)d_out;

    float4* pk = (float4*)d_ws;                  // 131072 * 16 B = 2 MiB scratch

    hipLaunchKernelGGL(pack_kernel, dim3(128), dim3(256), 0, stream, xyz, pk);
    hipLaunchKernelGGL(knn_kernel, dim3(NSMP / QPB), dim3(512), 0, stream,
                       pk, xyz, sxyz, temp, out);
}

// Round 7
// 71.878 us; speedup vs baseline: 3.5788x; 3.5788x over previous
//
#include <hip/hip_runtime.h>
#include <math.h>

#define NPTS 16384
#define NSMP 8192          // 8 * 1024
#define KNN 10
#define QPB 8              // queries per block (shared by all waves)
#define WAVES 8            // waves per block = point-range splits
#define SLICE (NPTS / WAVES)   // 2048 points per wave
#define GPW (SLICE / 128)      // 16 groups of 128 points per wave
#define CAP 192            // candidate buffer capacity per query

typedef float v2f __attribute__((ext_vector_type(2)));

// order-preserving float -> uint bijection
__device__ __forceinline__ unsigned mapf(float f) {
    unsigned u = __float_as_uint(f);
    return (u & 0x80000000u) ? ~u : (u | 0x80000000u);
}
__device__ __forceinline__ float unmapf(unsigned k) {
    unsigned u = (k & 0x80000000u) ? (k ^ 0x80000000u) : ~k;
    return __uint_as_float(u);
}

// Repack xyz into plane-paired layout per 128-point group g:
//   pk[(b*128+g)*128 + l]      = {x_l, x_{l+64}, y_l, y_{l+64}}
//   pk[(b*128+g)*128 + 64 + l] = {z_l, z_{l+64}, w_l, w_{l+64}}   (w = |p|^2)
// One thread per point-pair: 65536 threads.
__global__ __launch_bounds__(256) void pack_kernel(const float* __restrict__ xyz,
                                                   float4* __restrict__ pk) {
    const int t = blockIdx.x * 256 + threadIdx.x;
    const int b = t >> 13;          // batch
    const int r = t & 8191;
    const int g = r >> 6;           // group (128 pts)
    const int l = r & 63;           // lane slot
    const float* pA = xyz + ((size_t)b * NPTS + (size_t)g * 128 + l) * 3;
    const float* pB = pA + 64 * 3;
    const float xA = pA[0], yA = pA[1], zA = pA[2];
    const float xB = pB[0], yB = pB[1], zB = pB[2];
    const float wA = fmaf(xA, xA, fmaf(yA, yA, zA * zA));
    const float wB = fmaf(xB, xB, fmaf(yB, yB, zB * zB));
    float4* dst = pk + ((size_t)(b * 128 + g) * 128);
    dst[l]      = make_float4(xA, xB, yA, yB);
    dst[l + 64] = make_float4(zA, zB, wA, wB);
}

__global__ __launch_bounds__(512, 4) void knn_kernel(
    const float4* __restrict__ pk,
    const float* __restrict__ xyz,
    const float* __restrict__ sxyz,
    const float* __restrict__ temp,
    float* __restrict__ out)
{
    __shared__ float minBuf[QPB][WAVES * 64];   // 16 KB: 512 substream minima per query
    __shared__ float tauS[QPB];
    __shared__ int   cnt[QPB];
    __shared__ float candD[QPB][CAP];           // 6 KB
    __shared__ int   candI[QPB][CAP];           // 6 KB

    const int lane  = threadIdx.x & 63;
    const int w     = threadIdx.x >> 6;         // wave id = point split id (0..7)
    const int qbase = blockIdx.x * QPB;
    const int b     = qbase >> 10;              // batch (128 blocks/batch, no straddle)

    if (threadIdx.x < QPB) cnt[threadIdx.x] = 0;

    // query constants, broadcast into both halves for packed-f32 math
    v2f nqx2[QPB], nqy2[QPB], nqz2[QPB];
    #pragma unroll
    for (int q = 0; q < QPB; ++q) {
        const float* s = sxyz + (size_t)(qbase + q) * 3;
        const float ax = -2.f * s[0], ay = -2.f * s[1], az = -2.f * s[2];
        nqx2[q].x = ax; nqx2[q].y = ax;
        nqy2[q].x = ay; nqy2[q].y = ay;
        nqz2[q].x = az; nqz2[q].y = az;
    }

    const float4* pw = pk + (size_t)b * NPTS + (size_t)w * (GPW * 128) + lane;

    // ---------------- pass A: packed running min, 2 pts/lane/iter ----------------
    float mnA[QPB], mnB[QPB];
    #pragma unroll
    for (int q = 0; q < QPB; ++q) { mnA[q] = INFINITY; mnB[q] = INFINITY; }

    #pragma unroll 4
    for (int j = 0; j < GPW; ++j) {
        const float4 XY = pw[j * 128];          // {x0,x1,y0,y1}
        const float4 ZW = pw[j * 128 + 64];     // {z0,z1,w0,w1}
        v2f X2; X2.x = XY.x; X2.y = XY.y;
        v2f Y2; Y2.x = XY.z; Y2.y = XY.w;
        v2f Z2; Z2.x = ZW.x; Z2.y = ZW.y;
        v2f W2; W2.x = ZW.z; W2.y = ZW.w;
        #pragma unroll
        for (int q = 0; q < QPB; ++q) {
            // d' = |p|^2 - 2 p.q  (contracts to v_pk_fma_f32 chain)
            const v2f d2 = X2 * nqx2[q] + (Y2 * nqy2[q] + (Z2 * nqz2[q] + W2));
            mnA[q] = fminf(mnA[q], d2.x);
            mnB[q] = fminf(mnB[q], d2.y);
        }
    }
    #pragma unroll
    for (int q = 0; q < QPB; ++q) minBuf[q][w * 64 + lane] = fminf(mnA[q], mnB[q]);
    __syncthreads();

    // ------- threshold: wave w extracts 10th smallest of 512 minima (query w) -------
    {
        float r[8];
        #pragma unroll
        for (int k = 0; k < 8; ++k) r[k] = minBuf[w][lane + k * 64];
        float g = INFINITY;
        for (int kk = 0; kk < KNN; ++kk) {
            float v = r[0];
            #pragma unroll
            for (int k = 1; k < 8; ++k) v = fminf(v, r[k]);
            g = v;
            #pragma unroll
            for (int off = 32; off >= 1; off >>= 1) g = fminf(g, __shfl_xor(g, off));
            const unsigned long long mm = __ballot(v == g);
            if (lane == (int)__builtin_ctzll(mm)) {   // remove one instance
                if      (r[0] == g) r[0] = INFINITY;
                else if (r[1] == g) r[1] = INFINITY;
                else if (r[2] == g) r[2] = INFINITY;
                else if (r[3] == g) r[3] = INFINITY;
                else if (r[4] == g) r[4] = INFINITY;
                else if (r[5] == g) r[5] = INFINITY;
                else if (r[6] == g) r[6] = INFINITY;
                else                r[7] = INFINITY;
            }
        }
        if (lane == 0) tauS[w] = g;   // 10th smallest substream min >= d10 (provable)
    }
    __syncthreads();

    float tau[QPB];
    #pragma unroll
    for (int q = 0; q < QPB; ++q) tau[q] = tauS[q];

    // ---------------- pass B: filter d <= tau, parallel compaction ----------------
    const int sbase = w * SLICE;
    #pragma unroll 2
    for (int j = 0; j < GPW; ++j) {
        const float4 XY = pw[j * 128];
        const float4 ZW = pw[j * 128 + 64];
        v2f X2; X2.x = XY.x; X2.y = XY.y;
        v2f Y2; Y2.x = XY.z; Y2.y = XY.w;
        v2f Z2; Z2.x = ZW.x; Z2.y = ZW.y;
        v2f W2; W2.x = ZW.z; W2.y = ZW.w;
        v2f d2[QPB];
        float e = INFINITY;
        #pragma unroll
        for (int q = 0; q < QPB; ++q) {
            d2[q] = X2 * nqx2[q] + (Y2 * nqy2[q] + (Z2 * nqz2[q] + W2));
            e = fminf(e, fminf(d2[q].x, d2[q].y) - tau[q]);
        }
        if (__ballot(e <= 0.f)) {               // rare wave-uniform path
            #pragma unroll
            for (int q = 0; q < QPB; ++q) {
                const unsigned long long mA = __ballot(d2[q].x <= tau[q]);
                const unsigned long long mB = __ballot(d2[q].y <= tau[q]);
                if (mA | mB) {
                    const int cA  = __popcll(mA);
                    const int tot = cA + __popcll(mB);
                    const int leader = (int)__builtin_ctzll(mA | mB);
                    int base = 0;
                    if (lane == leader) base = atomicAdd(&cnt[q], tot);
                    base = __shfl(base, leader);
                    if (d2[q].x <= tau[q]) {
                        const int slot = base + __popcll(mA & ((1ull << lane) - 1ull));
                        if (slot < CAP) { candD[q][slot] = d2[q].x; candI[q][slot] = sbase + j * 128 + lane; }
                    }
                    if (d2[q].y <= tau[q]) {
                        const int slot = base + cA + __popcll(mB & ((1ull << lane) - 1ull));
                        if (slot < CAP) { candD[q][slot] = d2[q].y; candI[q][slot] = sbase + j * 128 + 64 + lane; }
                    }
                }
            }
        }
    }
    __syncthreads();

    // ------- final: wave w selects top-10 of query w's candidates (canonical) -------
    {
        const int q   = w;
        const int gid = qbase + q;
        const int c   = min(cnt[q], CAP);       // c >= 10 guaranteed

        unsigned long long k0 = (lane       < c) ? ((unsigned long long)mapf(candD[q][lane      ]) << 32) | (unsigned)candI[q][lane      ] : ~0ull;
        unsigned long long k1 = (lane +  64 < c) ? ((unsigned long long)mapf(candD[q][lane +  64]) << 32) | (unsigned)candI[q][lane +  64] : ~0ull;
        unsigned long long k2 = (lane + 128 < c) ? ((unsigned long long)mapf(candD[q][lane + 128]) << 32) | (unsigned)candI[q][lane + 128] : ~0ull;

        unsigned long long sel = ~0ull;
        for (int k = 0; k < KNN; ++k) {
            const unsigned long long a01 = (k0 < k1) ? k0 : k1;
            const unsigned long long v   = (a01 < k2) ? a01 : k2;
            unsigned long long g = v;
            #pragma unroll
            for (int off = 32; off >= 1; off >>= 1) {
                const unsigned long long o = __shfl_xor(g, off);
                g = (o < g) ? o : g;
            }
            if (lane == k) sel = g;             // lane k holds k-th smallest (sorted)
            const unsigned long long mm = __ballot(v == g);
            if (lane == (int)__builtin_ctzll(mm)) {
                if      (k0 == g) k0 = ~0ull;
                else if (k1 == g) k1 = ~0ull;
                else              k2 = ~0ull;
            }
        }

        // epilogue: d2 = max(d' + |q|^2, 0), softmax over 10, weighted coord sum
        const float* s = sxyz + (size_t)gid * 3;
        const float q2 = fmaf(s[0], s[0], fmaf(s[1], s[1], s[2] * s[2]));
        const float dp = unmapf((unsigned)(sel >> 32));
        const float d2v = fmaxf(dp + q2, 0.f);
        const float dmin = __shfl(d2v, 0);      // lane 0 = smallest (sorted order)
        const float t = temp[0];
        const float invt2 = 1.0f / (t * t);
        float wgt = 0.f, px = 0.f, py = 0.f, pz = 0.f;
        if (lane < KNN) {
            wgt = __expf((dmin - d2v) * invt2);
            const int idx = (int)(unsigned)(sel & 0xFFFFFFFFull);
            const float* pp = xyz + ((size_t)b * NPTS + idx) * 3;
            px = pp[0]; py = pp[1]; pz = pp[2];
        }
        float sw = wgt, sx = wgt * px, sy = wgt * py, sz = wgt * pz;
        #pragma unroll
        for (int off = 8; off >= 1; off >>= 1) {
            sw += __shfl_xor(sw, off);
            sx += __shfl_xor(sx, off);
            sy += __shfl_xor(sy, off);
            sz += __shfl_xor(sz, off);
        }
        if (lane == 0) {
            const float inv = 1.0f / sw;
            out[(size_t)gid * 3 + 0] = sx * inv;
            out[(size_t)gid * 3 + 1] = sy * inv;
            out[(size_t)gid * 3 + 2] = sz * inv;
            if (gid == 0) out[NSMP * 3] = t;    // tuple output 2: temp
        }
    }
}

extern "C" void kernel_launch(void* const* d_in, const int* in_sizes, int n_in,
                              void* d_out, int out_size, void* d_ws, size_t ws_size,
                              hipStream_t stream) {
    const float* xyz  = (const float*)d_in[0];   // [8,16384,3]
    const float* sxyz = (const float*)d_in[1];   // [8,1024,3]
    const float* temp = (const float*)d_in[2];   // scalar
    float* out = (float*)d_out;

    float4* pk = (float4*)d_ws;                  // 131072 * 16 B = 2 MiB scratch

    hipLaunchKernelGGL(pack_kernel, dim3(256), dim3(256), 0, stream, xyz, pk);
    hipLaunchKernelGGL(knn_kernel, dim3(NSMP / QPB), dim3(512), 0, stream,
                       pk, xyz, sxyz, temp, out);
}

// Round 8
// 66.394 us; speedup vs baseline: 3.8743x; 1.0826x over previous
//
#include <hip/hip_runtime.h>
#include <math.h>

#define NPTS 16384
#define NSMP 8192          // 8 * 1024
#define KNN 10
#define QPB 4              // queries per block (shared by all waves)
#define WAVES 4            // waves per block = point-range splits
#define SLICE (NPTS / WAVES)   // 4096 points per wave
#define GPW (SLICE / 128)      // 32 groups of 128 points per wave
#define CAP 256            // candidate buffer capacity per query

typedef float v2f __attribute__((ext_vector_type(2)));

// order-preserving float -> uint bijection
__device__ __forceinline__ unsigned mapf(float f) {
    unsigned u = __float_as_uint(f);
    return (u & 0x80000000u) ? ~u : (u | 0x80000000u);
}
__device__ __forceinline__ float unmapf(unsigned k) {
    unsigned u = (k & 0x80000000u) ? (k ^ 0x80000000u) : ~k;
    return __uint_as_float(u);
}

// Plane-paired layout per 128-point group g:
//   pk[(b*128+g)*128 + l]      = {x_l, x_{l+64}, y_l, y_{l+64}}
//   pk[(b*128+g)*128 + 64 + l] = {z_l, z_{l+64}, w_l, w_{l+64}}   (w = |p|^2)
__global__ __launch_bounds__(256) void pack_kernel(const float* __restrict__ xyz,
                                                   float4* __restrict__ pk) {
    const int t = blockIdx.x * 256 + threadIdx.x;   // 65536 threads = point pairs
    const int b = t >> 13;          // batch
    const int r = t & 8191;
    const int g = r >> 6;           // group (128 pts)
    const int l = r & 63;           // lane slot
    const float* pA = xyz + ((size_t)b * NPTS + (size_t)g * 128 + l) * 3;
    const float* pB = pA + 64 * 3;
    const float xA = pA[0], yA = pA[1], zA = pA[2];
    const float xB = pB[0], yB = pB[1], zB = pB[2];
    const float wA = fmaf(xA, xA, fmaf(yA, yA, zA * zA));
    const float wB = fmaf(xB, xB, fmaf(yB, yB, zB * zB));
    float4* dst = pk + ((size_t)(b * 128 + g) * 128);
    dst[l]      = make_float4(xA, xB, yA, yB);
    dst[l + 64] = make_float4(zA, zB, wA, wB);
}

__global__ __launch_bounds__(256) void knn_kernel(
    const float4* __restrict__ pk,
    const float* __restrict__ xyz,
    const float* __restrict__ sxyz,
    const float* __restrict__ temp,
    float* __restrict__ out)
{
    __shared__ float minBuf[QPB][WAVES * 64];   // 4 KB: 256 substream minima per query
    __shared__ float tauS[QPB];
    __shared__ int   cnt[QPB];
    __shared__ float candD[QPB][CAP];           // 4 KB
    __shared__ int   candI[QPB][CAP];           // 4 KB

    const int lane  = threadIdx.x & 63;
    const int w     = threadIdx.x >> 6;         // wave id = point split id (0..3)
    const int qbase = blockIdx.x * QPB;
    const int b     = qbase >> 10;              // batch (256 blocks/batch, no straddle)

    if (threadIdx.x < QPB) cnt[threadIdx.x] = 0;

    // query constants, broadcast into both halves for packed-f32 math
    v2f nqx2[QPB], nqy2[QPB], nqz2[QPB];
    #pragma unroll
    for (int q = 0; q < QPB; ++q) {
        const float* s = sxyz + (size_t)(qbase + q) * 3;
        const float ax = -2.f * s[0], ay = -2.f * s[1], az = -2.f * s[2];
        nqx2[q].x = ax; nqx2[q].y = ax;
        nqy2[q].x = ay; nqy2[q].y = ay;
        nqz2[q].x = az; nqz2[q].y = az;
    }

    const float4* pw = pk + (size_t)b * NPTS + (size_t)w * (GPW * 128) + lane;

    // ------- pass A: packed running min, 2 groups (4 points/lane) per iteration -------
    v2f mn[QPB];
    #pragma unroll
    for (int q = 0; q < QPB; ++q) { mn[q].x = INFINITY; mn[q].y = INFINITY; }

    #pragma unroll 2
    for (int j = 0; j < GPW; j += 2) {
        const float4 XY0 = pw[j * 128];         // {x0,x1,y0,y1}
        const float4 ZW0 = pw[j * 128 + 64];    // {z0,z1,w0,w1}
        const float4 XY1 = pw[j * 128 + 128];
        const float4 ZW1 = pw[j * 128 + 192];
        v2f X0; X0.x = XY0.x; X0.y = XY0.y;
        v2f Y0; Y0.x = XY0.z; Y0.y = XY0.w;
        v2f Z0; Z0.x = ZW0.x; Z0.y = ZW0.y;
        v2f W0; W0.x = ZW0.z; W0.y = ZW0.w;
        v2f X1; X1.x = XY1.x; X1.y = XY1.y;
        v2f Y1; Y1.x = XY1.z; Y1.y = XY1.w;
        v2f Z1; Z1.x = ZW1.x; Z1.y = ZW1.y;
        v2f W1; W1.x = ZW1.z; W1.y = ZW1.w;
        #pragma unroll
        for (int q = 0; q < QPB; ++q) {
            const v2f d0 = X0 * nqx2[q] + (Y0 * nqy2[q] + (Z0 * nqz2[q] + W0));
            const v2f d1 = X1 * nqx2[q] + (Y1 * nqy2[q] + (Z1 * nqz2[q] + W1));
            mn[q] = __builtin_elementwise_min(mn[q], __builtin_elementwise_min(d0, d1));
        }
    }
    #pragma unroll
    for (int q = 0; q < QPB; ++q) minBuf[q][w * 64 + lane] = fminf(mn[q].x, mn[q].y);
    __syncthreads();

    // ------- threshold: wave w extracts 10th smallest of 256 minima (query w) -------
    {
        float r0 = minBuf[w][lane      ];
        float r1 = minBuf[w][lane +  64];
        float r2 = minBuf[w][lane + 128];
        float r3 = minBuf[w][lane + 192];
        float g = INFINITY;
        for (int kk = 0; kk < KNN; ++kk) {
            const float v = fminf(fminf(r0, r1), fminf(r2, r3));
            g = v;
            #pragma unroll
            for (int off = 32; off >= 1; off >>= 1) g = fminf(g, __shfl_xor(g, off));
            const unsigned long long mm = __ballot(v == g);
            if (lane == (int)__builtin_ctzll(mm)) {   // remove one instance
                if      (r0 == g) r0 = INFINITY;
                else if (r1 == g) r1 = INFINITY;
                else if (r2 == g) r2 = INFINITY;
                else              r3 = INFINITY;
            }
        }
        if (lane == 0) tauS[w] = g;   // 10th smallest substream min >= d10 (provable)
    }
    __syncthreads();

    v2f tau2[QPB];
    float tau[QPB];
    #pragma unroll
    for (int q = 0; q < QPB; ++q) { tau[q] = tauS[q]; tau2[q].x = tau[q]; tau2[q].y = tau[q]; }

    // ---------------- pass B: filter d <= tau, parallel compaction ----------------
    const int sbase = w * SLICE;
    #pragma unroll 2
    for (int j = 0; j < GPW; ++j) {
        const float4 XY = pw[j * 128];
        const float4 ZW = pw[j * 128 + 64];
        v2f X2; X2.x = XY.x; X2.y = XY.y;
        v2f Y2; Y2.x = XY.z; Y2.y = XY.w;
        v2f Z2; Z2.x = ZW.x; Z2.y = ZW.y;
        v2f W2; W2.x = ZW.z; W2.y = ZW.w;
        v2f dv[QPB];
        v2f e;
        #pragma unroll
        for (int q = 0; q < QPB; ++q) {
            dv[q] = X2 * nqx2[q] + (Y2 * nqy2[q] + (Z2 * nqz2[q] + W2));
            const v2f eq = dv[q] - tau2[q];
            e = (q == 0) ? eq : __builtin_elementwise_min(e, eq);
        }
        if (__ballot(fminf(e.x, e.y) <= 0.f)) {
            #pragma unroll
            for (int q = 0; q < QPB; ++q) {
                const unsigned long long mA = __ballot(dv[q].x <= tau[q]);
                const unsigned long long mB = __ballot(dv[q].y <= tau[q]);
                if (mA | mB) {
                    const int cA  = __popcll(mA);
                    const int tot = cA + __popcll(mB);
                    const int leader = (int)__builtin_ctzll(mA | mB);
                    int base = 0;
                    if (lane == leader) base = atomicAdd(&cnt[q], tot);
                    base = __shfl(base, leader);
                    if (dv[q].x <= tau[q]) {
                        const int slot = base + __popcll(mA & ((1ull << lane) - 1ull));
                        if (slot < CAP) { candD[q][slot] = dv[q].x; candI[q][slot] = sbase + j * 128 + lane; }
                    }
                    if (dv[q].y <= tau[q]) {
                        const int slot = base + cA + __popcll(mB & ((1ull << lane) - 1ull));
                        if (slot < CAP) { candD[q][slot] = dv[q].y; candI[q][slot] = sbase + j * 128 + 64 + lane; }
                    }
                }
            }
        }
    }
    __syncthreads();

    // ------- final: wave w selects top-10 of query w's candidates (canonical) -------
    {
        const int q   = w;
        const int gid = qbase + q;
        const int c   = min(cnt[q], CAP);       // c >= 10 guaranteed

        unsigned long long k0 = (lane       < c) ? ((unsigned long long)mapf(candD[q][lane      ]) << 32) | (unsigned)candI[q][lane      ] : ~0ull;
        unsigned long long k1 = (lane +  64 < c) ? ((unsigned long long)mapf(candD[q][lane +  64]) << 32) | (unsigned)candI[q][lane +  64] : ~0ull;
        unsigned long long k2 = (lane + 128 < c) ? ((unsigned long long)mapf(candD[q][lane + 128]) << 32) | (unsigned)candI[q][lane + 128] : ~0ull;
        unsigned long long k3 = (lane + 192 < c) ? ((unsigned long long)mapf(candD[q][lane + 192]) << 32) | (unsigned)candI[q][lane + 192] : ~0ull;

        unsigned long long sel = ~0ull;
        for (int k = 0; k < KNN; ++k) {
            const unsigned long long a01 = (k0 < k1) ? k0 : k1;
            const unsigned long long a23 = (k2 < k3) ? k2 : k3;
            const unsigned long long v   = (a01 < a23) ? a01 : a23;
            unsigned long long g = v;
            #pragma unroll
            for (int off = 32; off >= 1; off >>= 1) {
                const unsigned long long o = __shfl_xor(g, off);
                g = (o < g) ? o : g;
            }
            if (lane == k) sel = g;             // lane k holds k-th smallest (sorted)
            const unsigned long long mm = __ballot(v == g);
            if (lane == (int)__builtin_ctzll(mm)) {
                if      (k0 == g) k0 = ~0ull;
                else if (k1 == g) k1 = ~0ull;
                else if (k2 == g) k2 = ~0ull;
                else              k3 = ~0ull;
            }
        }

        // epilogue: d2 = max(d' + |q|^2, 0), softmax over 10, weighted coord sum
        const float* s = sxyz + (size_t)gid * 3;
        const float q2 = fmaf(s[0], s[0], fmaf(s[1], s[1], s[2] * s[2]));
        const float dp = unmapf((unsigned)(sel >> 32));
        const float d2v = fmaxf(dp + q2, 0.f);
        const float dmin = __shfl(d2v, 0);      // lane 0 = smallest (sorted order)
        const float t = temp[0];
        const float invt2 = 1.0f / (t * t);
        float wgt = 0.f, px = 0.f, py = 0.f, pz = 0.f;
        if (lane < KNN) {
            wgt = __expf((dmin - d2v) * invt2);
            const int idx = (int)(unsigned)(sel & 0xFFFFFFFFull);
            const float* pp = xyz + ((size_t)b * NPTS + idx) * 3;
            px = pp[0]; py = pp[1]; pz = pp[2];
        }
        float sw = wgt, sx = wgt * px, sy = wgt * py, sz = wgt * pz;
        #pragma unroll
        for (int off = 8; off >= 1; off >>= 1) {
            sw += __shfl_xor(sw, off);
            sx += __shfl_xor(sx, off);
            sy += __shfl_xor(sy, off);
            sz += __shfl_xor(sz, off);
        }
        if (lane == 0) {
            const float inv = 1.0f / sw;
            out[(size_t)gid * 3 + 0] = sx * inv;
            out[(size_t)gid * 3 + 1] = sy * inv;
            out[(size_t)gid * 3 + 2] = sz * inv;
            if (gid == 0) out[NSMP * 3] = t;    // tuple output 2: temp
        }
    }
}

extern "C" void kernel_launch(void* const* d_in, const int* in_sizes, int n_in,
                              void* d_out, int out_size, void* d_ws, size_t ws_size,
                              hipStream_t stream) {
    const float* xyz  = (const float*)d_in[0];   // [8,16384,3]
    const float* sxyz = (const float*)d_in[1];   // [8,1024,3]
    const float* temp = (const float*)d_in[2];   // scalar
    float* out = (float*)d_out;

    float4* pk = (float4*)d_ws;                  // 131072 * 16 B = 2 MiB scratch

    hipLaunchKernelGGL(pack_kernel, dim3(256), dim3(256), 0, stream, xyz, pk);
    hipLaunchKernelGGL(knn_kernel, dim3(NSMP / QPB), dim3(256), 0, stream,
                       pk, xyz, sxyz, temp, out);
}

// Round 9
// 61.711 us; speedup vs baseline: 4.1684x; 1.0759x over previous
//
#include <hip/hip_runtime.h>
#include <math.h>

#define NPTS 16384
#define NSMP 8192          // 8 * 1024
#define KNN 10
#define QPB 8              // queries per block (shared by all waves)
#define WAVES 4            // waves per block = point-range splits
#define SLICE (NPTS / WAVES)   // 4096 points per wave
#define GPW (SLICE / 128)      // 32 groups of 128 points per wave
#define CAP 128            // candidate buffer capacity per query

typedef float v2f __attribute__((ext_vector_type(2)));

// order-preserving float -> uint bijection
__device__ __forceinline__ unsigned mapf(float f) {
    unsigned u = __float_as_uint(f);
    return (u & 0x80000000u) ? ~u : (u | 0x80000000u);
}
__device__ __forceinline__ float unmapf(unsigned k) {
    unsigned u = (k & 0x80000000u) ? (k ^ 0x80000000u) : ~k;
    return __uint_as_float(u);
}

// Plane-paired layout per 128-point group g:
//   pk[(b*128+g)*128 + l]      = {x_l, x_{l+64}, y_l, y_{l+64}}
//   pk[(b*128+g)*128 + 64 + l] = {z_l, z_{l+64}, w_l, w_{l+64}}   (w = |p|^2)
__global__ __launch_bounds__(256) void pack_kernel(const float* __restrict__ xyz,
                                                   float4* __restrict__ pk) {
    const int t = blockIdx.x * 256 + threadIdx.x;   // 65536 threads = point pairs
    const int b = t >> 13;          // batch
    const int r = t & 8191;
    const int g = r >> 6;           // group (128 pts)
    const int l = r & 63;           // lane slot
    const float* pA = xyz + ((size_t)b * NPTS + (size_t)g * 128 + l) * 3;
    const float* pB = pA + 64 * 3;
    const float xA = pA[0], yA = pA[1], zA = pA[2];
    const float xB = pB[0], yB = pB[1], zB = pB[2];
    const float wA = fmaf(xA, xA, fmaf(yA, yA, zA * zA));
    const float wB = fmaf(xB, xB, fmaf(yB, yB, zB * zB));
    float4* dst = pk + ((size_t)(b * 128 + g) * 128);
    dst[l]      = make_float4(xA, xB, yA, yB);
    dst[l + 64] = make_float4(zA, zB, wA, wB);
}

__global__ __launch_bounds__(256, 4) void knn_kernel(
    const float4* __restrict__ pk,
    const float* __restrict__ xyz,
    const float* __restrict__ sxyz,
    const float* __restrict__ temp,
    float* __restrict__ out)
{
    __shared__ float minBuf[QPB][WAVES * 64];   // 8 KB: 256 substream minima per query
    __shared__ float tauS[QPB];
    __shared__ int   cnt[QPB];
    __shared__ float candD[QPB][CAP];           // 4 KB
    __shared__ int   candI[QPB][CAP];           // 4 KB

    const int lane  = threadIdx.x & 63;
    const int w     = threadIdx.x >> 6;         // wave id = point split id (0..3)
    const int qbase = blockIdx.x * QPB;
    const int b     = qbase >> 10;              // batch (128 blocks/batch, no straddle)

    if (threadIdx.x < QPB) cnt[threadIdx.x] = 0;

    // query constants, broadcast into both halves for packed-f32 math
    v2f nqx2[QPB], nqy2[QPB], nqz2[QPB];
    #pragma unroll
    for (int q = 0; q < QPB; ++q) {
        const float* s = sxyz + (size_t)(qbase + q) * 3;
        const float ax = -2.f * s[0], ay = -2.f * s[1], az = -2.f * s[2];
        nqx2[q].x = ax; nqx2[q].y = ax;
        nqy2[q].x = ay; nqy2[q].y = ay;
        nqz2[q].x = az; nqz2[q].y = az;
    }

    const float4* pw = pk + (size_t)b * NPTS + (size_t)w * (GPW * 128) + lane;

    // ------- pass A: packed running min, 2 groups (4 points/lane) per iteration -------
    v2f mn[QPB];
    #pragma unroll
    for (int q = 0; q < QPB; ++q) { mn[q].x = INFINITY; mn[q].y = INFINITY; }

    for (int j = 0; j < GPW; j += 2) {
        const float4 XY0 = pw[j * 128];         // {x0,x1,y0,y1}
        const float4 ZW0 = pw[j * 128 + 64];    // {z0,z1,w0,w1}
        const float4 XY1 = pw[j * 128 + 128];
        const float4 ZW1 = pw[j * 128 + 192];
        v2f X0; X0.x = XY0.x; X0.y = XY0.y;
        v2f Y0; Y0.x = XY0.z; Y0.y = XY0.w;
        v2f Z0; Z0.x = ZW0.x; Z0.y = ZW0.y;
        v2f W0; W0.x = ZW0.z; W0.y = ZW0.w;
        v2f X1; X1.x = XY1.x; X1.y = XY1.y;
        v2f Y1; Y1.x = XY1.z; Y1.y = XY1.w;
        v2f Z1; Z1.x = ZW1.x; Z1.y = ZW1.y;
        v2f W1; W1.x = ZW1.z; W1.y = ZW1.w;
        #pragma unroll
        for (int q = 0; q < QPB; ++q) {
            const v2f d0 = X0 * nqx2[q] + (Y0 * nqy2[q] + (Z0 * nqz2[q] + W0));
            const v2f d1 = X1 * nqx2[q] + (Y1 * nqy2[q] + (Z1 * nqz2[q] + W1));
            mn[q] = __builtin_elementwise_min(mn[q], __builtin_elementwise_min(d0, d1));
        }
    }
    #pragma unroll
    for (int q = 0; q < QPB; ++q) minBuf[q][w * 64 + lane] = fminf(mn[q].x, mn[q].y);
    __syncthreads();

    // ------- threshold: wave w handles queries {w, w+4}.  tau = 10th smallest of the
    //         64 per-lane minima (each lane-min covers 256 pts).  Provably >= d10:
    //         at most 9 lanes can hold a point strictly below d10. -------
    #pragma unroll
    for (int rq = w; rq < QPB; rq += WAVES) {
        float v = fminf(fminf(minBuf[rq][lane], minBuf[rq][lane + 64]),
                        fminf(minBuf[rq][lane + 128], minBuf[rq][lane + 192]));
        float g = INFINITY;
        for (int kk = 0; kk < KNN; ++kk) {
            g = v;
            #pragma unroll
            for (int off = 32; off >= 1; off >>= 1) g = fminf(g, __shfl_xor(g, off));
            const unsigned long long mm = __ballot(v == g);
            if (lane == (int)__builtin_ctzll(mm)) v = INFINITY;  // remove that lane's min
        }
        if (lane == 0) tauS[rq] = g;
    }
    __syncthreads();

    v2f tau2[QPB];
    float tau[QPB];
    #pragma unroll
    for (int q = 0; q < QPB; ++q) { tau[q] = tauS[q]; tau2[q].x = tau[q]; tau2[q].y = tau[q]; }

    // ---------------- pass B: filter d <= tau, parallel compaction ----------------
    const int sbase = w * SLICE;
    float4 XY = pw[0];
    float4 ZW = pw[64];
    for (int j = 0; j < GPW; ++j) {
        // prefetch next group before the (divergent) trigger branch
        const int jn = (j + 1 < GPW) ? j + 1 : j;
        const float4 nXY = pw[jn * 128];
        const float4 nZW = pw[jn * 128 + 64];

        v2f X2; X2.x = XY.x; X2.y = XY.y;
        v2f Y2; Y2.x = XY.z; Y2.y = XY.w;
        v2f Z2; Z2.x = ZW.x; Z2.y = ZW.y;
        v2f W2; W2.x = ZW.z; W2.y = ZW.w;
        v2f dv[QPB];
        v2f e;
        #pragma unroll
        for (int q = 0; q < QPB; ++q) {
            dv[q] = X2 * nqx2[q] + (Y2 * nqy2[q] + (Z2 * nqz2[q] + W2));
            const v2f eq = dv[q] - tau2[q];
            e = (q == 0) ? eq : __builtin_elementwise_min(e, eq);
        }
        if (__ballot(fminf(e.x, e.y) <= 0.f)) {
            #pragma unroll
            for (int q = 0; q < QPB; ++q) {
                const unsigned long long mA = __ballot(dv[q].x <= tau[q]);
                const unsigned long long mB = __ballot(dv[q].y <= tau[q]);
                if (mA | mB) {
                    const int cA  = __popcll(mA);
                    const int tot = cA + __popcll(mB);
                    const int leader = (int)__builtin_ctzll(mA | mB);
                    int base = 0;
                    if (lane == leader) base = atomicAdd(&cnt[q], tot);
                    base = __shfl(base, leader);
                    if (dv[q].x <= tau[q]) {
                        const int slot = base + __popcll(mA & ((1ull << lane) - 1ull));
                        if (slot < CAP) { candD[q][slot] = dv[q].x; candI[q][slot] = sbase + j * 128 + lane; }
                    }
                    if (dv[q].y <= tau[q]) {
                        const int slot = base + cA + __popcll(mB & ((1ull << lane) - 1ull));
                        if (slot < CAP) { candD[q][slot] = dv[q].y; candI[q][slot] = sbase + j * 128 + 64 + lane; }
                    }
                }
            }
        }
        XY = nXY; ZW = nZW;
    }
    __syncthreads();

    // ------- final: wave w merges queries {w, w+4} (canonical (d,idx) order) -------
    const float t = temp[0];
    const float invt2 = 1.0f / (t * t);
    #pragma unroll
    for (int q = w; q < QPB; q += WAVES) {
        const int gid = qbase + q;
        const int c   = min(cnt[q], CAP);       // c >= 10 guaranteed

        unsigned long long k0 = (lane      < c) ? ((unsigned long long)mapf(candD[q][lane     ]) << 32) | (unsigned)candI[q][lane     ] : ~0ull;
        unsigned long long k1 = (lane + 64 < c) ? ((unsigned long long)mapf(candD[q][lane + 64]) << 32) | (unsigned)candI[q][lane + 64] : ~0ull;

        unsigned long long sel = ~0ull;
        for (int k = 0; k < KNN; ++k) {
            const unsigned long long v = (k0 < k1) ? k0 : k1;
            unsigned long long g = v;
            #pragma unroll
            for (int off = 32; off >= 1; off >>= 1) {
                const unsigned long long o = __shfl_xor(g, off);
                g = (o < g) ? o : g;
            }
            if (lane == k) sel = g;             // lane k holds k-th smallest (sorted)
            const unsigned long long mm = __ballot(v == g);
            if (lane == (int)__builtin_ctzll(mm)) {
                if (k0 == g) k0 = ~0ull;
                else         k1 = ~0ull;
            }
        }

        // epilogue: d2 = max(d' + |q|^2, 0), softmax over 10, weighted coord sum
        const float* s = sxyz + (size_t)gid * 3;
        const float q2 = fmaf(s[0], s[0], fmaf(s[1], s[1], s[2] * s[2]));
        const float dp = unmapf((unsigned)(sel >> 32));
        const float d2v = fmaxf(dp + q2, 0.f);
        const float dmin = __shfl(d2v, 0);      // lane 0 = smallest (sorted order)
        float wgt = 0.f, px = 0.f, py = 0.f, pz = 0.f;
        if (lane < KNN) {
            wgt = __expf((dmin - d2v) * invt2);
            const int idx = (int)(unsigned)(sel & 0xFFFFFFFFull);
            const float* pp = xyz + ((size_t)b * NPTS + idx) * 3;
            px = pp[0]; py = pp[1]; pz = pp[2];
        }
        float sw = wgt, sx = wgt * px, sy = wgt * py, sz = wgt * pz;
        #pragma unroll
        for (int off = 8; off >= 1; off >>= 1) {
            sw += __shfl_xor(sw, off);
            sx += __shfl_xor(sx, off);
            sy += __shfl_xor(sy, off);
            sz += __shfl_xor(sz, off);
        }
        if (lane == 0) {
            const float inv = 1.0f / sw;
            out[(size_t)gid * 3 + 0] = sx * inv;
            out[(size_t)gid * 3 + 1] = sy * inv;
            out[(size_t)gid * 3 + 2] = sz * inv;
            if (gid == 0) out[NSMP * 3] = t;    // tuple output 2: temp
        }
    }
}

extern "C" void kernel_launch(void* const* d_in, const int* in_sizes, int n_in,
                              void* d_out, int out_size, void* d_ws, size_t ws_size,
                              hipStream_t stream) {
    const float* xyz  = (const float*)d_in[0];   // [8,16384,3]
    const float* sxyz = (const float*)d_in[1];   // [8,1024,3]
    const float* temp = (const float*)d_in[2];   // scalar
    float* out = (float*)d_out;

    float4* pk = (float4*)d_ws;                  // 131072 * 16 B = 2 MiB scratch

    hipLaunchKernelGGL(pack_kernel, dim3(256), dim3(256), 0, stream, xyz, pk);
    hipLaunchKernelGGL(knn_kernel, dim3(NSMP / QPB), dim3(256), 0, stream,
                       pk, xyz, sxyz, temp, out);
}

// Round 10
// 61.347 us; speedup vs baseline: 4.1931x; 1.0059x over previous
//
#include <hip/hip_runtime.h>
#include <math.h>

#define NPTS 16384
#define NSMP 8192          // 8 * 1024
#define KNN 10
#define QPB 8              // queries per block (shared by all waves)
#define WAVES 4            // waves per block = point-range splits
#define SLICE (NPTS / WAVES)   // 4096 points per wave
#define GPW (SLICE / 128)      // 32 groups of 128 points per wave
#define CAP 128            // candidate buffer capacity per query

typedef float v2f __attribute__((ext_vector_type(2)));

// order-preserving float -> uint bijection
__device__ __forceinline__ unsigned mapf(float f) {
    unsigned u = __float_as_uint(f);
    return (u & 0x80000000u) ? ~u : (u | 0x80000000u);
}
__device__ __forceinline__ float unmapf(unsigned k) {
    unsigned u = (k & 0x80000000u) ? (k ^ 0x80000000u) : ~k;
    return __uint_as_float(u);
}

// Plane-paired layout per 128-point group g:
//   pk[(b*128+g)*128 + l]      = {x_l, x_{l+64}, y_l, y_{l+64}}
//   pk[(b*128+g)*128 + 64 + l] = {z_l, z_{l+64}, w_l, w_{l+64}}   (w = |p|^2)
__global__ __launch_bounds__(256) void pack_kernel(const float* __restrict__ xyz,
                                                   float4* __restrict__ pk) {
    const int t = blockIdx.x * 256 + threadIdx.x;   // 65536 threads = point pairs
    const int b = t >> 13;          // batch
    const int r = t & 8191;
    const int g = r >> 6;           // group (128 pts)
    const int l = r & 63;           // lane slot
    const float* pA = xyz + ((size_t)b * NPTS + (size_t)g * 128 + l) * 3;
    const float* pB = pA + 64 * 3;
    const float xA = pA[0], yA = pA[1], zA = pA[2];
    const float xB = pB[0], yB = pB[1], zB = pB[2];
    const float wA = fmaf(xA, xA, fmaf(yA, yA, zA * zA));
    const float wB = fmaf(xB, xB, fmaf(yB, yB, zB * zB));
    float4* dst = pk + ((size_t)(b * 128 + g) * 128);
    dst[l]      = make_float4(xA, xB, yA, yB);
    dst[l + 64] = make_float4(zA, zB, wA, wB);
}

__global__ __launch_bounds__(256, 4) void knn_kernel(
    const float4* __restrict__ pk,
    const float* __restrict__ xyz,
    const float* __restrict__ sxyz,
    const float* __restrict__ temp,
    float* __restrict__ out)
{
    __shared__ float minBuf[QPB][WAVES * 64];   // 8 KB: 256 substream minima per query
    __shared__ float tauS[QPB];
    __shared__ int   cnt[QPB];
    __shared__ float candD[QPB][CAP];           // 4 KB
    __shared__ int   candI[QPB][CAP];           // 4 KB

    const int lane  = threadIdx.x & 63;
    const int w     = threadIdx.x >> 6;         // wave id = point split id (0..3)
    const int qbase = blockIdx.x * QPB;
    const int b     = qbase >> 10;              // batch (128 blocks/batch, no straddle)

    if (threadIdx.x < QPB) cnt[threadIdx.x] = 0;

    // query constants (wave-uniform -> compiler keeps in SGPRs), premul by -2
    v2f nqx2[QPB], nqy2[QPB], nqz2[QPB];
    #pragma unroll
    for (int q = 0; q < QPB; ++q) {
        const float* s = sxyz + (size_t)(qbase + q) * 3;
        const float ax = -2.f * s[0], ay = -2.f * s[1], az = -2.f * s[2];
        nqx2[q].x = ax; nqx2[q].y = ax;
        nqy2[q].x = ay; nqy2[q].y = ay;
        nqz2[q].x = az; nqz2[q].y = az;
    }

    const float4* pw = pk + (size_t)b * NPTS + (size_t)w * (GPW * 128) + lane;

    // ------- pass A: packed running min, 2 groups/iter, 2-group-ahead prefetch -------
    v2f mn0[QPB], mn1[QPB];
    #pragma unroll
    for (int q = 0; q < QPB; ++q) {
        mn0[q].x = INFINITY; mn0[q].y = INFINITY;
        mn1[q].x = INFINITY; mn1[q].y = INFINITY;
    }

    float4 XY0 = pw[0], ZW0 = pw[64], XY1 = pw[128], ZW1 = pw[192];
    for (int j = 0; j < GPW; j += 2) {
        const float4* pn = pw + (size_t)((j + 2 < GPW) ? j + 2 : j) * 128;
        const float4 aXY0 = pn[0], aZW0 = pn[64], aXY1 = pn[128], aZW1 = pn[192];

        const v2f X0 = {XY0.x, XY0.y}, Y0 = {XY0.z, XY0.w};
        const v2f Z0 = {ZW0.x, ZW0.y}, W0 = {ZW0.z, ZW0.w};
        const v2f X1 = {XY1.x, XY1.y}, Y1 = {XY1.z, XY1.w};
        const v2f Z1 = {ZW1.x, ZW1.y}, W1 = {ZW1.z, ZW1.w};
        #pragma unroll
        for (int q = 0; q < QPB; ++q) {
            const v2f d0 = X0 * nqx2[q] + (Y0 * nqy2[q] + (Z0 * nqz2[q] + W0));
            const v2f d1 = X1 * nqx2[q] + (Y1 * nqy2[q] + (Z1 * nqz2[q] + W1));
            mn0[q] = __builtin_elementwise_min(mn0[q], d0);
            mn1[q] = __builtin_elementwise_min(mn1[q], d1);
        }
        XY0 = aXY0; ZW0 = aZW0; XY1 = aXY1; ZW1 = aZW1;
    }
    #pragma unroll
    for (int q = 0; q < QPB; ++q) {
        const v2f m = __builtin_elementwise_min(mn0[q], mn1[q]);
        minBuf[q][w * 64 + lane] = fminf(m.x, m.y);
    }
    __syncthreads();

    // ------- threshold: wave w handles queries {w, w+4}.  tau = 10th smallest of the
    //         64 per-lane minima (each lane-min covers 256 pts).  Provably >= d10. -------
    #pragma unroll
    for (int rq = w; rq < QPB; rq += WAVES) {
        float v = fminf(fminf(minBuf[rq][lane], minBuf[rq][lane + 64]),
                        fminf(minBuf[rq][lane + 128], minBuf[rq][lane + 192]));
        float g = INFINITY;
        for (int kk = 0; kk < KNN; ++kk) {
            g = v;
            #pragma unroll
            for (int off = 32; off >= 1; off >>= 1) g = fminf(g, __shfl_xor(g, off));
            const unsigned long long mm = __ballot(v == g);
            if (lane == (int)__builtin_ctzll(mm)) v = INFINITY;  // remove that lane's min
        }
        if (lane == 0) tauS[rq] = g;
    }
    __syncthreads();

    v2f tau2[QPB];
    #pragma unroll
    for (int q = 0; q < QPB; ++q) { tau2[q].x = tauS[q]; tau2[q].y = tauS[q]; }

    // ------- pass B: filter d <= tau, per-lane atomic compaction, prefetched -------
    const int sbase = w * SLICE;
    XY0 = pw[0]; ZW0 = pw[64]; XY1 = pw[128]; ZW1 = pw[192];
    for (int j = 0; j < GPW; j += 2) {
        const float4* pn = pw + (size_t)((j + 2 < GPW) ? j + 2 : j) * 128;
        const float4 aXY0 = pn[0], aZW0 = pn[64], aXY1 = pn[128], aZW1 = pn[192];

        const v2f X0 = {XY0.x, XY0.y}, Y0 = {XY0.z, XY0.w};
        const v2f Z0 = {ZW0.x, ZW0.y}, W0 = {ZW0.z, ZW0.w};
        const v2f X1 = {XY1.x, XY1.y}, Y1 = {XY1.z, XY1.w};
        const v2f Z1 = {ZW1.x, ZW1.y}, W1 = {ZW1.z, ZW1.w};
        const int idx0 = sbase + j * 128 + lane;    // group j, half A
        #pragma unroll
        for (int q = 0; q < QPB; ++q) {
            const float tq = tau2[q].x;
            const v2f d0 = X0 * nqx2[q] + (Y0 * nqy2[q] + (Z0 * nqz2[q] + W0));
            const v2f d1 = X1 * nqx2[q] + (Y1 * nqy2[q] + (Z1 * nqz2[q] + W1));
            const v2f m01 = __builtin_elementwise_min(d0, d1);
            if (__ballot(fminf(m01.x, m01.y) <= tq)) {
                if (d0.x <= tq) { const int s = atomicAdd(&cnt[q], 1);
                    if (s < CAP) { candD[q][s] = d0.x; candI[q][s] = idx0; } }
                if (d0.y <= tq) { const int s = atomicAdd(&cnt[q], 1);
                    if (s < CAP) { candD[q][s] = d0.y; candI[q][s] = idx0 + 64; } }
                if (d1.x <= tq) { const int s = atomicAdd(&cnt[q], 1);
                    if (s < CAP) { candD[q][s] = d1.x; candI[q][s] = idx0 + 128; } }
                if (d1.y <= tq) { const int s = atomicAdd(&cnt[q], 1);
                    if (s < CAP) { candD[q][s] = d1.y; candI[q][s] = idx0 + 192; } }
            }
        }
        XY0 = aXY0; ZW0 = aZW0; XY1 = aXY1; ZW1 = aZW1;
    }
    __syncthreads();

    // ------- final: wave w merges queries {w, w+4} via canonical (d,idx) sort -------
    const float t = temp[0];
    const float invt2 = 1.0f / (t * t);
    #pragma unroll
    for (int q = w; q < QPB; q += WAVES) {
        const int gid = qbase + q;
        const int c   = min(cnt[q], CAP);       // c >= 10 guaranteed

        unsigned long long k0 = (lane      < c) ? ((unsigned long long)mapf(candD[q][lane     ]) << 32) | (unsigned)candI[q][lane     ] : ~0ull;
        unsigned long long k1 = (lane + 64 < c) ? ((unsigned long long)mapf(candD[q][lane + 64]) << 32) | (unsigned)candI[q][lane + 64] : ~0ull;

        unsigned long long sel = ~0ull;
        for (int k = 0; k < KNN; ++k) {
            const unsigned long long v = (k0 < k1) ? k0 : k1;
            unsigned long long g = v;
            #pragma unroll
            for (int off = 32; off >= 1; off >>= 1) {
                const unsigned long long o = __shfl_xor(g, off);
                g = (o < g) ? o : g;
            }
            if (lane == k) sel = g;             // lane k holds k-th smallest (sorted)
            const unsigned long long mm = __ballot(v == g);
            if (lane == (int)__builtin_ctzll(mm)) {
                if (k0 == g) k0 = ~0ull;
                else         k1 = ~0ull;
            }
        }

        // epilogue: d2 = max(d' + |q|^2, 0), softmax over 10, weighted coord sum
        const float* s = sxyz + (size_t)gid * 3;
        const float q2 = fmaf(s[0], s[0], fmaf(s[1], s[1], s[2] * s[2]));
        const float dp = unmapf((unsigned)(sel >> 32));
        const float d2v = fmaxf(dp + q2, 0.f);
        const float dmin = __shfl(d2v, 0);      // lane 0 = smallest (sorted order)
        float wgt = 0.f, px = 0.f, py = 0.f, pz = 0.f;
        if (lane < KNN) {
            wgt = __expf((dmin - d2v) * invt2);
            const int idx = (int)(unsigned)(sel & 0xFFFFFFFFull);
            const float* pp = xyz + ((size_t)b * NPTS + idx) * 3;
            px = pp[0]; py = pp[1]; pz = pp[2];
        }
        float sw = wgt, sx = wgt * px, sy = wgt * py, sz = wgt * pz;
        #pragma unroll
        for (int off = 8; off >= 1; off >>= 1) {
            sw += __shfl_xor(sw, off);
            sx += __shfl_xor(sx, off);
            sy += __shfl_xor(sy, off);
            sz += __shfl_xor(sz, off);
        }
        if (lane == 0) {
            const float inv = 1.0f / sw;
            out[(size_t)gid * 3 + 0] = sx * inv;
            out[(size_t)gid * 3 + 1] = sy * inv;
            out[(size_t)gid * 3 + 2] = sz * inv;
            if (gid == 0) out[NSMP * 3] = t;    // tuple output 2: temp
        }
    }
}

extern "C" void kernel_launch(void* const* d_in, const int* in_sizes, int n_in,
                              void* d_out, int out_size, void* d_ws, size_t ws_size,
                              hipStream_t stream) {
    const float* xyz  = (const float*)d_in[0];   // [8,16384,3]
    const float* sxyz = (const float*)d_in[1];   // [8,1024,3]
    const float* temp = (const float*)d_in[2];   // scalar
    float* out = (float*)d_out;

    float4* pk = (float4*)d_ws;                  // 131072 * 16 B = 2 MiB scratch

    hipLaunchKernelGGL(pack_kernel, dim3(256), dim3(256), 0, stream, xyz, pk);
    hipLaunchKernelGGL(knn_kernel, dim3(NSMP / QPB), dim3(256), 0, stream,
                       pk, xyz, sxyz, temp, out);
}

// Round 11
// 55.641 us; speedup vs baseline: 4.6232x; 1.1026x over previous
//
#include <hip/hip_runtime.h>
#include <math.h>

#define NPTS 16384
#define NSMP 8192          // 8 * 1024
#define KNN 10
#define QPB 8              // queries per block (shared by all waves)
#define WAVES 4            // waves per block = point-range splits
#define SLICE (NPTS / WAVES)   // 4096 points per wave
#define GPW (SLICE / 128)      // 32 groups of 128 points per wave
#define CAP 128            // candidate buffer capacity per query

typedef float v2f __attribute__((ext_vector_type(2)));
typedef unsigned long long u64;

// order-preserving float -> uint bijection
__device__ __forceinline__ unsigned mapf(float f) {
    unsigned u = __float_as_uint(f);
    return (u & 0x80000000u) ? ~u : (u | 0x80000000u);
}
__device__ __forceinline__ float unmapf(unsigned k) {
    unsigned u = (k & 0x80000000u) ? (k ^ 0x80000000u) : ~k;
    return __uint_as_float(u);
}

// Plane-paired layout per 128-point group g:
//   pk[(b*128+g)*128 + l]      = {x_l, x_{l+64}, y_l, y_{l+64}}
//   pk[(b*128+g)*128 + 64 + l] = {z_l, z_{l+64}, w_l, w_{l+64}}   (w = |p|^2)
__global__ __launch_bounds__(256) void pack_kernel(const float* __restrict__ xyz,
                                                   float4* __restrict__ pk) {
    const int t = blockIdx.x * 256 + threadIdx.x;   // 65536 threads = point pairs
    const int b = t >> 13;          // batch
    const int r = t & 8191;
    const int g = r >> 6;           // group (128 pts)
    const int l = r & 63;           // lane slot
    const float* pA = xyz + ((size_t)b * NPTS + (size_t)g * 128 + l) * 3;
    const float* pB = pA + 64 * 3;
    const float xA = pA[0], yA = pA[1], zA = pA[2];
    const float xB = pB[0], yB = pB[1], zB = pB[2];
    const float wA = fmaf(xA, xA, fmaf(yA, yA, zA * zA));
    const float wB = fmaf(xB, xB, fmaf(yB, yB, zB * zB));
    float4* dst = pk + ((size_t)(b * 128 + g) * 128);
    dst[l]      = make_float4(xA, xB, yA, yB);
    dst[l + 64] = make_float4(zA, zB, wA, wB);
}

__global__ __launch_bounds__(256, 4) void knn_kernel(
    const float4* __restrict__ pk,
    const float* __restrict__ xyz,
    const float* __restrict__ sxyz,
    const float* __restrict__ temp,
    float* __restrict__ out)
{
    __shared__ float minBuf[QPB][WAVES * 64];   // 8 KB: 256 substream minima per query
    __shared__ unsigned tauU[QPB];
    __shared__ int   cnt[QPB];
    __shared__ u64   candK[QPB][CAP];           // 8 KB: canonical (mapf(d)<<32)|idx keys
    __shared__ u64   sort10[QPB][KNN];

    const int lane  = threadIdx.x & 63;
    const int w     = threadIdx.x >> 6;         // wave id = point split id (0..3)
    const int qbase = blockIdx.x * QPB;
    const int b     = qbase >> 10;              // batch (128 blocks/batch, no straddle)

    if (threadIdx.x < QPB) cnt[threadIdx.x] = 0;

    // query constants (wave-uniform -> SGPRs), premultiplied by -2
    v2f nqx2[QPB], nqy2[QPB], nqz2[QPB];
    #pragma unroll
    for (int q = 0; q < QPB; ++q) {
        const float* s = sxyz + (size_t)(qbase + q) * 3;
        const float ax = -2.f * s[0], ay = -2.f * s[1], az = -2.f * s[2];
        nqx2[q].x = ax; nqx2[q].y = ax;
        nqy2[q].x = ay; nqy2[q].y = ay;
        nqz2[q].x = az; nqz2[q].y = az;
    }

    const float4* pw = pk + (size_t)b * NPTS + (size_t)w * (GPW * 128) + lane;

    // ------- pass A: packed running min, 2 groups/iter, TWO-iteration-deep prefetch -------
    v2f mn0[QPB], mn1[QPB];
    #pragma unroll
    for (int q = 0; q < QPB; ++q) {
        mn0[q].x = INFINITY; mn0[q].y = INFINITY;
        mn1[q].x = INFINITY; mn1[q].y = INFINITY;
    }

    float4 c0 = pw[0],   c1 = pw[64],  c2 = pw[128], c3 = pw[192];
    float4 n0 = pw[256], n1 = pw[320], n2 = pw[384], n3 = pw[448];
    #pragma unroll 1
    for (int j = 0; j < GPW; j += 2) {
        const float4* pf = pw + (size_t)((j + 4 < GPW) ? j + 4 : j) * 128;
        const float4 f0 = pf[0], f1 = pf[64], f2 = pf[128], f3 = pf[192];

        const v2f X0 = {c0.x, c0.y}, Y0 = {c0.z, c0.w};
        const v2f Z0 = {c1.x, c1.y}, W0 = {c1.z, c1.w};
        const v2f X1 = {c2.x, c2.y}, Y1 = {c2.z, c2.w};
        const v2f Z1 = {c3.x, c3.y}, W1 = {c3.z, c3.w};
        #pragma unroll
        for (int q = 0; q < QPB; ++q) {
            const v2f d0 = X0 * nqx2[q] + (Y0 * nqy2[q] + (Z0 * nqz2[q] + W0));
            const v2f d1 = X1 * nqx2[q] + (Y1 * nqy2[q] + (Z1 * nqz2[q] + W1));
            mn0[q] = __builtin_elementwise_min(mn0[q], d0);
            mn1[q] = __builtin_elementwise_min(mn1[q], d1);
        }
        c0 = n0; c1 = n1; c2 = n2; c3 = n3;
        n0 = f0; n1 = f1; n2 = f2; n3 = f3;
    }
    #pragma unroll
    for (int q = 0; q < QPB; ++q) {
        const v2f m = __builtin_elementwise_min(mn0[q], mn1[q]);
        minBuf[q][w * 64 + lane] = fminf(m.x, m.y);
    }
    __syncthreads();

    // ------- tau: wave w handles queries {w, w+4} via binary search on mapped bits.
    //         v = per-lane min folded across the 4 waves (64 substreams of 256 pts).
    //         Invariant: count(v <= unmapf(hi)) >= 10  =>  tau >= 10th substream min >= d10. -------
    #pragma unroll
    for (int qi = 0; qi < 2; ++qi) {
        const int rq = w + qi * WAVES;
        const float v = fminf(fminf(minBuf[rq][lane], minBuf[rq][lane + 64]),
                              fminf(minBuf[rq][lane + 128], minBuf[rq][lane + 192]));
        const unsigned uv = mapf(v);
        unsigned lo = 0u, hi = 0xFFFFFFFFu;
        #pragma unroll 1
        for (int it = 0; it < 16; ++it) {
            const unsigned mid = lo + ((hi - lo) >> 1);
            const int c = __popcll(__ballot(uv <= mid));
            if (c >= KNN) hi = mid; else lo = mid + 1;
        }
        if (lane == 0) tauU[rq] = hi;
    }
    __syncthreads();

    float tau[QPB];
    #pragma unroll
    for (int q = 0; q < QPB; ++q) tau[q] = unmapf(tauU[q]);

    // ------- pass B: filter d <= tau, per-lane atomic compaction of u64 keys -------
    const int sbase = w * SLICE;
    c0 = pw[0]; c1 = pw[64]; c2 = pw[128]; c3 = pw[192];
    #pragma unroll 1
    for (int j = 0; j < GPW; j += 2) {
        const float4* pn = pw + (size_t)((j + 2 < GPW) ? j + 2 : j) * 128;
        const float4 a0 = pn[0], a1 = pn[64], a2 = pn[128], a3 = pn[192];

        const v2f X0 = {c0.x, c0.y}, Y0 = {c0.z, c0.w};
        const v2f Z0 = {c1.x, c1.y}, W0 = {c1.z, c1.w};
        const v2f X1 = {c2.x, c2.y}, Y1 = {c2.z, c2.w};
        const v2f Z1 = {c3.x, c3.y}, W1 = {c3.z, c3.w};
        const int idx0 = sbase + j * 128 + lane;    // group j, half A
        #pragma unroll
        for (int q = 0; q < QPB; ++q) {
            const float tq = tau[q];
            const v2f d0 = X0 * nqx2[q] + (Y0 * nqy2[q] + (Z0 * nqz2[q] + W0));
            const v2f d1 = X1 * nqx2[q] + (Y1 * nqy2[q] + (Z1 * nqz2[q] + W1));
            const v2f m01 = __builtin_elementwise_min(d0, d1);
            if (__ballot(fminf(m01.x, m01.y) <= tq)) {
                if (d0.x <= tq) { const int s = atomicAdd(&cnt[q], 1);
                    if (s < CAP) candK[q][s] = ((u64)mapf(d0.x) << 32) | (unsigned)idx0; }
                if (d0.y <= tq) { const int s = atomicAdd(&cnt[q], 1);
                    if (s < CAP) candK[q][s] = ((u64)mapf(d0.y) << 32) | (unsigned)(idx0 + 64); }
                if (d1.x <= tq) { const int s = atomicAdd(&cnt[q], 1);
                    if (s < CAP) candK[q][s] = ((u64)mapf(d1.x) << 32) | (unsigned)(idx0 + 128); }
                if (d1.y <= tq) { const int s = atomicAdd(&cnt[q], 1);
                    if (s < CAP) candK[q][s] = ((u64)mapf(d1.y) << 32) | (unsigned)(idx0 + 192); }
            }
        }
        c0 = a0; c1 = a1; c2 = a2; c3 = a3;
    }
    __syncthreads();

    // ------- final: wave w merges queries {w, w+4} by PARALLEL RANK (no shuffle chains).
    //         Keys are unique (idx in low bits) -> ranks unique -> canonical sorted top-10. -------
    const float t = temp[0];
    const float invt2 = 1.0f / (t * t);
    #pragma unroll 1
    for (int qi = 0; qi < 2; ++qi) {
        const int q   = w + qi * WAVES;
        const int gid = qbase + q;
        const int c   = min(cnt[q], CAP);       // c >= 10 guaranteed

        const u64 k0 = (lane      < c) ? candK[q][lane]      : ~0ull;
        const u64 k1 = (lane + 64 < c) ? candK[q][lane + 64] : ~0ull;
        int r0 = 0, r1 = 0;
        for (int jj = 0; jj < c; ++jj) {
            const u64 kj = candK[q][jj];        // LDS broadcast read
            r0 += (kj < k0) ? 1 : 0;
            r1 += (kj < k1) ? 1 : 0;
        }
        if (lane      < c && r0 < KNN) sort10[q][r0] = k0;
        if (lane + 64 < c && r1 < KNN) sort10[q][r1] = k1;
        __syncthreads();                        // uniform: all waves run both iterations

        const u64 sel = (lane < KNN) ? sort10[q][lane] : ~0ull;

        // epilogue: d2 = max(d' + |q|^2, 0), softmax over 10, weighted coord sum
        const float* s = sxyz + (size_t)gid * 3;
        const float q2 = fmaf(s[0], s[0], fmaf(s[1], s[1], s[2] * s[2]));
        const float dp = unmapf((unsigned)(sel >> 32));
        const float d2v = fmaxf(dp + q2, 0.f);
        const float dmin = __shfl(d2v, 0);      // lane 0 = rank 0 = smallest
        float wgt = 0.f, px = 0.f, py = 0.f, pz = 0.f;
        if (lane < KNN) {
            wgt = __expf((dmin - d2v) * invt2);
            const int idx = (int)(unsigned)(sel & 0xFFFFFFFFull);
            const float* pp = xyz + ((size_t)b * NPTS + idx) * 3;
            px = pp[0]; py = pp[1]; pz = pp[2];
        }
        float sw = wgt, sx = wgt * px, sy = wgt * py, sz = wgt * pz;
        #pragma unroll
        for (int off = 8; off >= 1; off >>= 1) {
            sw += __shfl_xor(sw, off);
            sx += __shfl_xor(sx, off);
            sy += __shfl_xor(sy, off);
            sz += __shfl_xor(sz, off);
        }
        if (lane == 0) {
            const float inv = 1.0f / sw;
            out[(size_t)gid * 3 + 0] = sx * inv;
            out[(size_t)gid * 3 + 1] = sy * inv;
            out[(size_t)gid * 3 + 2] = sz * inv;
            if (gid == 0) out[NSMP * 3] = t;    // tuple output 2: temp
        }
    }
}

extern "C" void kernel_launch(void* const* d_in, const int* in_sizes, int n_in,
                              void* d_out, int out_size, void* d_ws, size_t ws_size,
                              hipStream_t stream) {
    const float* xyz  = (const float*)d_in[0];   // [8,16384,3]
    const float* sxyz = (const float*)d_in[1];   // [8,1024,3]
    const float* temp = (const float*)d_in[2];   // scalar
    float* out = (float*)d_out;

    float4* pk = (float4*)d_ws;                  // 131072 * 16 B = 2 MiB scratch

    hipLaunchKernelGGL(pack_kernel, dim3(256), dim3(256), 0, stream, xyz, pk);
    hipLaunchKernelGGL(knn_kernel, dim3(NSMP / QPB), dim3(256), 0, stream,
                       pk, xyz, sxyz, temp, out);
}